// Round 4
// baseline (20354.231 us; speedup 1.0000x reference)
//
#include <hip/hip_runtime.h>
#include <stdint.h>

#define NPTS 8192
#define CDIM 128
#define KNNK 16
#define WPAD 136
#define WELEM (CDIM*WPAD)          // 17408 elems per transposed weight image
#define SCALE 0.08838834764831845f
#define FLDS_BYTES 78848
#define GRES 32
#define NCELL (GRES*GRES*GRES)

typedef __attribute__((ext_vector_type(4))) float f32x4;
typedef __attribute__((ext_vector_type(8))) short s16x8;

__device__ __forceinline__ unsigned short to_bf16(float f){
  union { float f; unsigned int u; } v; v.f = f;
  return (unsigned short)((v.u + 0x7fffu + ((v.u >> 16) & 1u)) >> 16);
}

__device__ __forceinline__ s16x8 cvt8(const float* p){
  float4 lo = *(const float4*)p;
  float4 hi = *(const float4*)(p + 4);
  s16x8 f;
  f[0]=(short)to_bf16(lo.x); f[1]=(short)to_bf16(lo.y);
  f[2]=(short)to_bf16(lo.z); f[3]=(short)to_bf16(lo.w);
  f[4]=(short)to_bf16(hi.x); f[5]=(short)to_bf16(hi.y);
  f[6]=(short)to_bf16(hi.z); f[7]=(short)to_bf16(hi.w);
  return f;
}

__device__ __forceinline__ unsigned mapf_u(unsigned s){
  return s ^ (0x80000000u | (unsigned)(((int)s) >> 31));
}
__device__ __forceinline__ float unmapf_u(unsigned u){
  unsigned r = (u & 0x80000000u) ? (u ^ 0x80000000u) : ~u;
  return __uint_as_float(r);
}

// ---------------- zero_init: counts + bbox ----------------
__global__ __launch_bounds__(256) void zero_init_kernel(int* __restrict__ counts,
                                                        unsigned* __restrict__ bbox)
{
  int t = blockIdx.x*256 + threadIdx.x;
  if (t < 2*NCELL) counts[t] = 0;
  if (t < 12) bbox[t] = ((t % 6) < 3) ? 0xFFFFFFFFu : 0u;   // lo-slots=max, hi-slots=min
}

// ---------------- prep: weights->bf16 images, pos4 pack, bbox reduce ----------------
__global__ __launch_bounds__(256) void prep_kernel(
    const float* __restrict__ Wq, const float* __restrict__ Wk,
    const float* __restrict__ Wv, const float* __restrict__ Wp2,
    const float* __restrict__ Wg1, const float* __restrict__ Wg2,
    const float* __restrict__ pos,
    unsigned short* __restrict__ wt, float4* __restrict__ pos4,
    unsigned* __restrict__ bbox)
{
  int t = blockIdx.x*256 + threadIdx.x;
  if (t < 6*WELEM){
    int w = t / WELEM, rem = t % WELEM, c = rem / WPAD, i = rem % WPAD;
    const float* src = (w==0)?Wq:(w==1)?Wk:(w==2)?Wv:(w==3)?Wp2:(w==4)?Wg1:Wg2;
    float v = (i < CDIM) ? src[i*CDIM + c] : 0.0f;
    if (w == 1) v = -v;                     // store -Wk so k folds into the t accumulator
    wt[t] = to_bf16(v);
  } else {
    int m = t - 6*WELEM;                    // < 16384, wave-aligned to batch
    float xx = pos[m*3+0], yy = pos[m*3+1], zz = pos[m*3+2];
    float p2 = __fadd_rn(__fadd_rn(__fmul_rn(xx,xx), __fmul_rn(yy,yy)), __fmul_rn(zz,zz));
    pos4[m] = make_float4(xx, yy, zz, p2);
    // wave-level bbox reduce (mapped u32), one atomic set per wave
    unsigned mnx = mapf_u(__float_as_uint(xx)), mny = mapf_u(__float_as_uint(yy)), mnz = mapf_u(__float_as_uint(zz));
    unsigned mxx = mnx, mxy = mny, mxz = mnz;
#pragma unroll
    for (int off = 1; off < 64; off <<= 1){
      mnx = min(mnx, (unsigned)__shfl_xor((int)mnx, off));
      mny = min(mny, (unsigned)__shfl_xor((int)mny, off));
      mnz = min(mnz, (unsigned)__shfl_xor((int)mnz, off));
      mxx = max(mxx, (unsigned)__shfl_xor((int)mxx, off));
      mxy = max(mxy, (unsigned)__shfl_xor((int)mxy, off));
      mxz = max(mxz, (unsigned)__shfl_xor((int)mxz, off));
    }
    if ((threadIdx.x & 63) == 0){
      int b = m >> 13;
      atomicMin(&bbox[b*6+0], mnx); atomicMin(&bbox[b*6+1], mny); atomicMin(&bbox[b*6+2], mnz);
      atomicMax(&bbox[b*6+3], mxx); atomicMax(&bbox[b*6+4], mxy); atomicMax(&bbox[b*6+5], mxz);
    }
  }
}

// ---------------- bin_count ----------------
__global__ __launch_bounds__(256) void bin_count_kernel(
    const float4* __restrict__ pos4, const unsigned* __restrict__ bbox,
    int* __restrict__ counts, int* __restrict__ cellId)
{
  int m = blockIdx.x*256 + threadIdx.x;       // < 16384
  int b = m >> 13;
  float4 p = pos4[m];
  float lox = unmapf_u(bbox[b*6+0]), loy = unmapf_u(bbox[b*6+1]), loz = unmapf_u(bbox[b*6+2]);
  float hix = unmapf_u(bbox[b*6+3]), hiy = unmapf_u(bbox[b*6+4]), hiz = unmapf_u(bbox[b*6+5]);
  int ix = min(GRES-1, max(0, (int)((p.x - lox) * ((float)GRES/(hix-lox)))));
  int iy = min(GRES-1, max(0, (int)((p.y - loy) * ((float)GRES/(hiy-loy)))));
  int iz = min(GRES-1, max(0, (int)((p.z - loz) * ((float)GRES/(hiz-loz)))));
  int cid = (iz*GRES + iy)*GRES + ix;
  cellId[m] = cid;
  atomicAdd(&counts[b*NCELL + cid], 1);
}

// ---------------- scan: per-batch exclusive prefix over NCELL counts ----------------
__global__ __launch_bounds__(1024) void scan_kernel(
    const int* __restrict__ counts, int* __restrict__ starts, int* __restrict__ cursor)
{
  __shared__ int part[1024];
  int b = blockIdx.x, t = threadIdx.x;
  const int* c = counts + b*NCELL;
  int* s = starts + b*(NCELL+1);
  int* cur = cursor + b*NCELL;
  int base = t*32, sum = 0;
  for (int i = 0; i < 32; ++i) sum += c[base+i];
  part[t] = sum; __syncthreads();
  for (int off = 1; off < 1024; off <<= 1){
    int v = (t >= off) ? part[t-off] : 0;
    __syncthreads();
    part[t] += v;
    __syncthreads();
  }
  int run = (t > 0) ? part[t-1] : 0;
  for (int i = 0; i < 32; ++i){ int cc = c[base+i]; s[base+i] = run; cur[base+i] = run; run += cc; }
  if (t == 1023) s[NCELL] = run;
}

// ---------------- scatter: cell-sorted pos4 + original idx ----------------
__global__ __launch_bounds__(256) void scatter_kernel(
    const float4* __restrict__ pos4, const int* __restrict__ cellId,
    int* __restrict__ cursor, float4* __restrict__ spos4, int* __restrict__ sidx)
{
  int m = blockIdx.x*256 + threadIdx.x;
  int b = m >> 13;
  int dst = atomicAdd(&cursor[b*NCELL + cellId[m]], 1);
  spos4[(b<<13) + dst] = pos4[m];
  sidx [(b<<13) + dst] = m & (NPTS-1);
}

// ---------------- kNN: one wave per query, expanding grid rings, exact top-16 ----------------
__global__ __launch_bounds__(256) void knn_grid_kernel(
    const float4* __restrict__ pos4, const float4* __restrict__ spos4,
    const int* __restrict__ sidx, const int* __restrict__ starts,
    const unsigned* __restrict__ bbox, int* __restrict__ idxout)
{
  const int tid = threadIdx.x, lane = tid & 63;
  const int g = blockIdx.x*4 + (tid >> 6);
  const int b = g >> 13, n = g & (NPTS-1);
  const float4 q = pos4[((size_t)b<<13) + n];
  const float4* sp = spos4 + ((size_t)b<<13);
  const int*    si = sidx  + ((size_t)b<<13);
  const int*    st = starts + b*(NCELL+1);

  float lox = unmapf_u(bbox[b*6+0]), loy = unmapf_u(bbox[b*6+1]), loz = unmapf_u(bbox[b*6+2]);
  float hix = unmapf_u(bbox[b*6+3]), hiy = unmapf_u(bbox[b*6+4]), hiz = unmapf_u(bbox[b*6+5]);
  float cwx = (hix-lox)*(1.0f/GRES), cwy = (hiy-loy)*(1.0f/GRES), cwz = (hiz-loz)*(1.0f/GRES);
  int cx = min(GRES-1, max(0, (int)((q.x - lox) * ((float)GRES/(hix-lox)))));
  int cy = min(GRES-1, max(0, (int)((q.y - loy) * ((float)GRES/(hiy-loy)))));
  int cz = min(GRES-1, max(0, (int)((q.z - loz) * ((float)GRES/(hiz-loz)))));

  unsigned khi = 0xFFFFFFFFu, klo = 0xFFFFFFFFu;   // distributed sorted list (lanes 0..15 per row)
  float Tf = __builtin_inff();

  auto insert = [&](unsigned ihi, unsigned ilo){
    unsigned phi = (unsigned)__builtin_amdgcn_update_dpp(0, (int)khi, 0x111, 0xF, 0xF, false);
    unsigned plo = (unsigned)__builtin_amdgcn_update_dpp(0, (int)klo, 0x111, 0xF, 0xF, false);
    bool gt  = (khi > ihi) || (khi == ihi && klo > ilo);
    bool pgt = ((lane & 15) != 0) && ((phi > ihi) || (phi == ihi && plo > ilo));
    khi = gt ? (pgt ? phi : ihi) : khi;
    klo = gt ? (pgt ? plo : ilo) : klo;
  };
  auto updT = [&](){
    unsigned t15 = (unsigned)__builtin_amdgcn_readlane((int)khi, 15);
    Tf = (t15 >= 0xFF800000u) ? __builtin_inff() : unmapf_u(t15);
  };

  for (int R = 1; R <= GRES-1; ++R){
    const int w = 2*R+1, w2 = w*w, nbox = w2*w;
    const bool first = (R == 1);
    for (int base = 0; base < nbox; base += 64){
      int e = base + lane;
      unsigned iz = (unsigned)e / (unsigned)w2;
      unsigned rem = (unsigned)e - iz*w2;
      unsigned iy = rem / (unsigned)w;
      unsigned ix = rem - iy*w;
      int dxx = (int)ix - R, dyy = (int)iy - R, dzz = (int)iz - R;
      int cheb = max(abs(dxx), max(abs(dyy), abs(dzz)));
      int gx = cx + dxx, gy = cy + dyy, gz = cz + dzz;
      bool take = (e < nbox) && (first || cheb == R)
               && gx >= 0 && gx < GRES && gy >= 0 && gy < GRES && gz >= 0 && gz < GRES;
      int cid = (gz*GRES + gy)*GRES + gx;
      int s0 = 0, s1 = 0;
      if (take){ s0 = st[cid]; s1 = st[cid+1]; }
      unsigned long long cm = __ballot(take && (s1 > s0));
      while (cm){
        int sl = (int)__builtin_ctzll(cm); cm &= cm - 1;
        int cs = __builtin_amdgcn_readlane(s0, sl);
        int ce = __builtin_amdgcn_readlane(s1, sl);
        for (int p0 = cs; p0 < ce; p0 += 64){
          int mm = p0 + lane;
          bool v = mm < ce;
          float4 c; int oi;
          if (v){ c = sp[mm]; oi = si[mm]; }
          else  { c = make_float4(0.f,0.f,0.f,__builtin_inff()); oi = 0x7fffffff; }
          float dot = __builtin_fmaf(c.z, q.z, __builtin_fmaf(c.y, q.y, __fmul_rn(c.x, q.x)));
          float d2  = __fsub_rn(__fadd_rn(q.w, c.w), __fadd_rn(dot, dot));
          bool ins = v && (d2 <= Tf);
          unsigned long long im = __ballot(ins);
          if (im){
            while (im){
              int s = (int)__builtin_ctzll(im); im &= im - 1;
              unsigned dvb = (unsigned)__builtin_amdgcn_readlane((int)__float_as_uint(d2), s);
              int ov = __builtin_amdgcn_readlane(oi, s);
              insert(mapf_u(dvb), (unsigned)ov);
            }
            updT();
          }
        }
      }
    }
    // termination: nearest possible point beyond ring R
    float bxlo = lox + (float)(cx-R)*cwx, bxhi = lox + (float)(cx+R+1)*cwx;
    float bylo = loy + (float)(cy-R)*cwy, byhi = loy + (float)(cy+R+1)*cwy;
    float bzlo = loz + (float)(cz-R)*cwz, bzhi = loz + (float)(cz+R+1)*cwz;
    float dxm = fmaxf(0.f, fmaxf(bxlo - q.x, q.x - bxhi));
    float dym = fmaxf(0.f, fmaxf(bylo - q.y, q.y - byhi));
    float dzm = fmaxf(0.f, fmaxf(bzlo - q.z, q.z - bzhi));
    float dmin2 = dxm*dxm + dym*dym + dzm*dzm;
    bool full = (cx-R <= 0) && (cx+R >= GRES-1) && (cy-R <= 0) && (cy+R >= GRES-1)
             && (cz-R <= 0) && (cz+R >= GRES-1);
    if (full) break;
    if (Tf + 1e-4f + Tf*1e-5f < dmin2) break;   // Tf=+inf while list unfilled -> keep going
  }
  if (lane < KNNK) idxout[(size_t)g*KNNK + lane] = (int)klo;
}

// ---------------- fused transform: 4 waves x 2 points, single-slot staging ----------------
__global__ __launch_bounds__(256, 2) void fused_kernel(
    const float* __restrict__ x, const float* __restrict__ pos,
    const float* __restrict__ bq, const float* __restrict__ bk,
    const float* __restrict__ bv, const float* __restrict__ Wp1,
    const float* __restrict__ bp1, const float* __restrict__ bp2,
    const float* __restrict__ bg1, const float* __restrict__ bg2,
    const int* __restrict__ idxws, const unsigned short* __restrict__ wt,
    float* __restrict__ out)
{
  extern __shared__ char smem[];
  unsigned short* WTl = (unsigned short*)smem;               // 1 slot: 34816 B
  float* q_lds = (float*)(smem + 34816);                     // [8][128] f32 = 4096
  unsigned short* t_base = (unsigned short*)(smem + 38912);  // 4 waves x [2][16][136] = 34816
  float* blds = (float*)(smem + 73728);                      // 1280 f32

  const int tid = threadIdx.x;
  const int lane = tid & 63, w = tid >> 6;
  const int r = lane & 15, grp = lane >> 4;
  const int pbase = blockIdx.x * 8;
  const int b = pbase >> 13;

  auto stageW = [&](int s){
    const float4* src = (const float4*)(wt + (size_t)s*WELEM);
    float4* dst = (float4*)smem;
    for (int cix = tid; cix < WELEM/8; cix += 256) dst[cix] = src[cix];
  };
  auto ldB = [&](int ct, int kk) -> s16x8 {
    return *(const s16x8*)&WTl[(ct*16 + r)*WPAD + kk*32 + grp*8];
  };

  for (int e = tid; e < 1280; e += 256){
    float v;
    if      (e < 128)  v = bq[e];
    else if (e < 256)  v = bk[e-128];
    else if (e < 384)  v = bv[e-256];
    else if (e < 512)  v = bp2[e-384];
    else if (e < 640)  v = bg1[e-512];
    else if (e < 768)  v = bg2[e-640];
    else if (e < 896)  v = bp1[e-768];
    else               v = Wp1[e-896];
    blds[e] = v;
  }
  stageW(0);   // Wq

  int nbr[2]; float relx[2], rely[2], relz[2];
#pragma unroll
  for (int j = 0; j < 2; ++j){
    int gp = pbase + w*2 + j;
    nbr[j] = idxws[(size_t)gp*KNNK + r];
    const float* pq = pos + (size_t)gp*3;
    const float* pn = pos + ((size_t)b*NPTS + nbr[j])*3;
    relx[j] = pq[0]-pn[0]; rely[j] = pq[1]-pn[1]; relz[j] = pq[2]-pn[2];
  }
  s16x8 qa[4];
  {
    const float* xr = x + (size_t)(pbase + (r & 7))*CDIM;
#pragma unroll
    for (int kk = 0; kk < 4; ++kk) qa[kk] = cvt8(xr + kk*32 + grp*8);
  }
  __syncthreads();

  {
    f32x4 qacc[2] = { {0.f,0.f,0.f,0.f}, {0.f,0.f,0.f,0.f} };
#pragma unroll
    for (int c2 = 0; c2 < 2; ++c2){
      int ct = w*2 + c2;
#pragma unroll
      for (int kk = 0; kk < 4; ++kk)
        qacc[c2] = __builtin_amdgcn_mfma_f32_16x16x32_bf16(qa[kk], ldB(ct,kk), qacc[c2], 0,0,0);
    }
#pragma unroll
    for (int c2 = 0; c2 < 2; ++c2){
      int col = (w*2+c2)*16 + r;
#pragma unroll
      for (int jj = 0; jj < 4; ++jj){
        int row = grp*4 + jj;
        if (row < 8) q_lds[row*CDIM + col] = qacc[c2][jj] + blds[col];
      }
    }
  }
  s16x8 pf[2][4];
#pragma unroll
  for (int j = 0; j < 2; ++j)
#pragma unroll
    for (int kk = 0; kk < 4; ++kk){
      s16x8 f;
#pragma unroll
      for (int i = 0; i < 8; ++i){
        int kc = kk*32 + grp*8 + i;
        float s = relx[j]*blds[896+kc] + rely[j]*blds[1024+kc] + relz[j]*blds[1152+kc] + blds[768+kc];
        f[i] = (short)to_bf16(fmaxf(s, 0.f));
      }
      pf[j][kk] = f;
    }
  __syncthreads();
  stageW(3);         // Wp2
  __syncthreads();

  f32x4 at[2][8], av[2][8];
#pragma unroll
  for (int j=0;j<2;++j)
#pragma unroll
    for (int ct=0;ct<8;++ct) at[j][ct] = (f32x4){0.f,0.f,0.f,0.f};
#pragma unroll
  for (int ct=0;ct<8;++ct)
#pragma unroll
    for (int kk=0;kk<4;++kk){
      s16x8 bw = ldB(ct,kk);
#pragma unroll
      for (int j=0;j<2;++j)
        at[j][ct] = __builtin_amdgcn_mfma_f32_16x16x32_bf16(pf[j][kk], bw, at[j][ct], 0,0,0);
    }
#pragma unroll
  for (int j=0;j<2;++j)
#pragma unroll
    for (int ct=0;ct<8;++ct) av[j][ct] = at[j][ct];
  s16x8 nf[2][4];
#pragma unroll
  for (int j=0;j<2;++j)
#pragma unroll
    for (int kk=0;kk<4;++kk)
      nf[j][kk] = cvt8(x + ((size_t)b*NPTS + nbr[j])*CDIM + kk*32 + grp*8);

  __syncthreads();
  stageW(1);         // -Wk
  __syncthreads();
#pragma unroll
  for (int ct=0;ct<8;++ct)
#pragma unroll
    for (int kk=0;kk<4;++kk){
      s16x8 bw = ldB(ct,kk);
#pragma unroll
      for (int j=0;j<2;++j) at[j][ct] = __builtin_amdgcn_mfma_f32_16x16x32_bf16(nf[j][kk], bw, at[j][ct], 0,0,0);
    }
  __syncthreads();
  stageW(2);         // Wv
  __syncthreads();
#pragma unroll
  for (int ct=0;ct<8;++ct)
#pragma unroll
    for (int kk=0;kk<4;++kk){
      s16x8 bw = ldB(ct,kk);
#pragma unroll
      for (int j=0;j<2;++j) av[j][ct] = __builtin_amdgcn_mfma_f32_16x16x32_bf16(nf[j][kk], bw, av[j][ct], 0,0,0);
    }
#pragma unroll
  for (int j=0;j<2;++j){
    int prow = (w*2+j)*CDIM;
#pragma unroll
    for (int ct=0;ct<8;++ct){
      int col = ct*16+r;
      float add = q_lds[prow+col] + blds[384+col] - blds[128+col];
#pragma unroll
      for (int jj=0;jj<4;++jj) at[j][ct][jj] = (at[j][ct][jj] + add)*SCALE;
    }
  }
  __syncthreads();
  stageW(4);         // Wg1
  __syncthreads();

  unsigned short* tl = t_base + w*(2*16*WPAD);
#pragma unroll
  for (int j=0;j<2;++j)
#pragma unroll
    for (int ct=0;ct<8;++ct)
#pragma unroll
      for (int jj=0;jj<4;++jj)
        tl[(j*16 + grp*4+jj)*WPAD + ct*16 + r] = to_bf16(at[j][ct][jj]);
  s16x8 tf[2][4];
#pragma unroll
  for (int j=0;j<2;++j)
#pragma unroll
    for (int kk=0;kk<4;++kk)
      tf[j][kk] = *(const s16x8*)&tl[(j*16 + r)*WPAD + kk*32 + grp*8];
  f32x4 hacc[2][8];
#pragma unroll
  for (int j=0;j<2;++j)
#pragma unroll
    for (int ct=0;ct<8;++ct) hacc[j][ct] = (f32x4){0.f,0.f,0.f,0.f};
#pragma unroll
  for (int ct=0;ct<8;++ct)
#pragma unroll
    for (int kk=0;kk<4;++kk){
      s16x8 bw = ldB(ct,kk);
#pragma unroll
      for (int j=0;j<2;++j)
        hacc[j][ct] = __builtin_amdgcn_mfma_f32_16x16x32_bf16(tf[j][kk], bw, hacc[j][ct], 0,0,0);
    }
  __syncthreads();
  stageW(5);         // Wg2
  __syncthreads();
#pragma unroll
  for (int j=0;j<2;++j)
#pragma unroll
    for (int ct=0;ct<8;++ct){
      int col = ct*16+r; float bb = blds[512+col];
#pragma unroll
      for (int jj=0;jj<4;++jj)
        tl[(j*16+grp*4+jj)*WPAD + ct*16 + r] = to_bf16(fmaxf(hacc[j][ct][jj]+bb, 0.f));
    }
  s16x8 hf[2][4];
#pragma unroll
  for (int j=0;j<2;++j)
#pragma unroll
    for (int kk=0;kk<4;++kk)
      hf[j][kk] = *(const s16x8*)&tl[(j*16 + r)*WPAD + kk*32 + grp*8];
  f32x4 gacc[2][8];
#pragma unroll
  for (int j=0;j<2;++j)
#pragma unroll
    for (int ct=0;ct<8;++ct) gacc[j][ct] = (f32x4){0.f,0.f,0.f,0.f};
#pragma unroll
  for (int ct=0;ct<8;++ct)
#pragma unroll
    for (int kk=0;kk<4;++kk){
      s16x8 bw = ldB(ct,kk);
#pragma unroll
      for (int j=0;j<2;++j)
        gacc[j][ct] = __builtin_amdgcn_mfma_f32_16x16x32_bf16(hf[j][kk], bw, gacc[j][ct], 0,0,0);
    }
#pragma unroll
  for (int j=0;j<2;++j){
#pragma unroll
    for (int ct=0;ct<8;++ct){
      int col = ct*16+r;
      float gb = blds[640+col];
      float g0v = gacc[j][ct][0]+gb, g1v = gacc[j][ct][1]+gb;
      float g2v = gacc[j][ct][2]+gb, g3v = gacc[j][ct][3]+gb;
      float mx = fmaxf(fmaxf(g0v,g1v), fmaxf(g2v,g3v));
      mx = fmaxf(mx, __shfl_xor(mx,16));
      mx = fmaxf(mx, __shfl_xor(mx,32));
      float e0=__expf(g0v-mx), e1=__expf(g1v-mx), e2=__expf(g2v-mx), e3=__expf(g3v-mx);
      float vb = blds[256+col] + blds[384+col];
      float ss = e0+e1+e2+e3;
      float oo = e0*(av[j][ct][0]+vb) + e1*(av[j][ct][1]+vb)
               + e2*(av[j][ct][2]+vb) + e3*(av[j][ct][3]+vb);
      ss += __shfl_xor(ss,16); ss += __shfl_xor(ss,32);
      oo += __shfl_xor(oo,16); oo += __shfl_xor(oo,32);
      if (grp == 0) out[(size_t)(pbase + w*2 + j)*CDIM + col] = oo/ss;
    }
  }
}

extern "C" void kernel_launch(void* const* d_in, const int* in_sizes, int n_in,
                              void* d_out, int out_size, void* d_ws, size_t ws_size,
                              hipStream_t stream)
{
  const float* x    = (const float*)d_in[0];
  const float* pos  = (const float*)d_in[1];
  const float* Wq   = (const float*)d_in[2];
  const float* bq   = (const float*)d_in[3];
  const float* Wk   = (const float*)d_in[4];
  const float* bk   = (const float*)d_in[5];
  const float* Wv   = (const float*)d_in[6];
  const float* bv   = (const float*)d_in[7];
  const float* Wp1  = (const float*)d_in[8];
  const float* bp1  = (const float*)d_in[9];
  const float* Wp2  = (const float*)d_in[10];
  const float* bp2  = (const float*)d_in[11];
  const float* Wg1  = (const float*)d_in[12];
  const float* bg1  = (const float*)d_in[13];
  const float* Wg2  = (const float*)d_in[14];
  const float* bg2  = (const float*)d_in[15];
  float* out = (float*)d_out;

  char* ws = (char*)d_ws;
  int*            idxs   = (int*)ws;                          // 1,048,576
  unsigned short* wt     = (unsigned short*)(ws + 1048576);   //   208,896
  float4*         pos4   = (float4*)(ws + 1257472);           //   262,144
  float4*         spos4  = (float4*)(ws + 1519616);           //   262,144
  int*            sidxp  = (int*)(ws + 1781760);              //    65,536
  int*            cellId = (int*)(ws + 1847296);              //    65,536
  int*            counts = (int*)(ws + 1912832);              //   262,144
  int*            starts = (int*)(ws + 2174976);              //   262,400
  int*            cursor = (int*)(ws + 2437376);              //   262,144
  unsigned*       bbox   = (unsigned*)(ws + 2699520);         //        48

  hipFuncSetAttribute((const void*)fused_kernel,
                      hipFuncAttributeMaxDynamicSharedMemorySize, FLDS_BYTES);

  zero_init_kernel<<<256, 256, 0, stream>>>(counts, bbox);
  prep_kernel<<<472, 256, 0, stream>>>(Wq, Wk, Wv, Wp2, Wg1, Wg2, pos, wt, pos4, bbox);
  bin_count_kernel<<<64, 256, 0, stream>>>(pos4, bbox, counts, cellId);
  scan_kernel<<<2, 1024, 0, stream>>>(counts, starts, cursor);
  scatter_kernel<<<64, 256, 0, stream>>>(pos4, cellId, cursor, spos4, sidxp);
  knn_grid_kernel<<<4096, 256, 0, stream>>>(pos4, spos4, sidxp, starts, bbox, idxs);
  fused_kernel<<<2048, 256, FLDS_BYTES, stream>>>(x, pos, bq, bk, bv, Wp1, bp1, bp2,
                                                  bg1, bg2, idxs, wt, out);
}

// Round 5
// 391.198 us; speedup vs baseline: 52.0305x; 52.0305x over previous
//
#include <hip/hip_runtime.h>
#include <stdint.h>

#define NPTS 8192
#define CDIM 128
#define KNNK 16
#define WPAD 136
#define WELEM (CDIM*WPAD)          // 17408 elems per transposed weight image
#define SCALE 0.08838834764831845f
#define FLDS_BYTES 78848
#define GRES 32
#define NCELL (GRES*GRES*GRES)

typedef __attribute__((ext_vector_type(4))) float f32x4;
typedef __attribute__((ext_vector_type(8))) short s16x8;

__device__ __forceinline__ unsigned short to_bf16(float f){
  union { float f; unsigned int u; } v; v.f = f;
  return (unsigned short)((v.u + 0x7fffu + ((v.u >> 16) & 1u)) >> 16);
}

__device__ __forceinline__ s16x8 cvt8(const float* p){
  float4 lo = *(const float4*)p;
  float4 hi = *(const float4*)(p + 4);
  s16x8 f;
  f[0]=(short)to_bf16(lo.x); f[1]=(short)to_bf16(lo.y);
  f[2]=(short)to_bf16(lo.z); f[3]=(short)to_bf16(lo.w);
  f[4]=(short)to_bf16(hi.x); f[5]=(short)to_bf16(hi.y);
  f[6]=(short)to_bf16(hi.z); f[7]=(short)to_bf16(hi.w);
  return f;
}

__device__ __forceinline__ unsigned mapf_u(unsigned s){
  return s ^ (0x80000000u | (unsigned)(((int)s) >> 31));
}
__device__ __forceinline__ float unmapf_u(unsigned u){
  unsigned r = (u & 0x80000000u) ? (u ^ 0x80000000u) : ~u;
  return __uint_as_float(r);
}

// ---------------- zero_init: counts + bbox ----------------
__global__ __launch_bounds__(256) void zero_init_kernel(int* __restrict__ counts,
                                                        unsigned* __restrict__ bbox)
{
  int t = blockIdx.x*256 + threadIdx.x;
  if (t < 2*NCELL) counts[t] = 0;
  if (t < 12) bbox[t] = ((t % 6) < 3) ? 0xFFFFFFFFu : 0u;   // lo-slots=max, hi-slots=min
}

// ---------------- prep: weights->bf16 images, pos4 pack, bbox reduce ----------------
__global__ __launch_bounds__(256) void prep_kernel(
    const float* __restrict__ Wq, const float* __restrict__ Wk,
    const float* __restrict__ Wv, const float* __restrict__ Wp2,
    const float* __restrict__ Wg1, const float* __restrict__ Wg2,
    const float* __restrict__ pos,
    unsigned short* __restrict__ wt, float4* __restrict__ pos4,
    unsigned* __restrict__ bbox)
{
  int t = blockIdx.x*256 + threadIdx.x;
  if (t < 6*WELEM){
    int w = t / WELEM, rem = t % WELEM, c = rem / WPAD, i = rem % WPAD;
    const float* src = (w==0)?Wq:(w==1)?Wk:(w==2)?Wv:(w==3)?Wp2:(w==4)?Wg1:Wg2;
    float v = (i < CDIM) ? src[i*CDIM + c] : 0.0f;
    if (w == 1) v = -v;                     // store -Wk so k folds into the t accumulator
    wt[t] = to_bf16(v);
  } else {
    int m = t - 6*WELEM;                    // < 16384, wave-aligned to batch
    float xx = pos[m*3+0], yy = pos[m*3+1], zz = pos[m*3+2];
    float p2 = __fadd_rn(__fadd_rn(__fmul_rn(xx,xx), __fmul_rn(yy,yy)), __fmul_rn(zz,zz));
    pos4[m] = make_float4(xx, yy, zz, p2);
    // wave-level bbox reduce (mapped u32), one atomic set per wave
    unsigned mnx = mapf_u(__float_as_uint(xx)), mny = mapf_u(__float_as_uint(yy)), mnz = mapf_u(__float_as_uint(zz));
    unsigned mxx = mnx, mxy = mny, mxz = mnz;
#pragma unroll
    for (int off = 1; off < 64; off <<= 1){
      mnx = min(mnx, (unsigned)__shfl_xor((int)mnx, off));
      mny = min(mny, (unsigned)__shfl_xor((int)mny, off));
      mnz = min(mnz, (unsigned)__shfl_xor((int)mnz, off));
      mxx = max(mxx, (unsigned)__shfl_xor((int)mxx, off));
      mxy = max(mxy, (unsigned)__shfl_xor((int)mxy, off));
      mxz = max(mxz, (unsigned)__shfl_xor((int)mxz, off));
    }
    if ((threadIdx.x & 63) == 0){
      int b = m >> 13;
      atomicMin(&bbox[b*6+0], mnx); atomicMin(&bbox[b*6+1], mny); atomicMin(&bbox[b*6+2], mnz);
      atomicMax(&bbox[b*6+3], mxx); atomicMax(&bbox[b*6+4], mxy); atomicMax(&bbox[b*6+5], mxz);
    }
  }
}

// ---------------- bin_count ----------------
__global__ __launch_bounds__(256) void bin_count_kernel(
    const float4* __restrict__ pos4, const unsigned* __restrict__ bbox,
    int* __restrict__ counts, int* __restrict__ cellId)
{
  int m = blockIdx.x*256 + threadIdx.x;       // < 16384
  int b = m >> 13;
  float4 p = pos4[m];
  float lox = unmapf_u(bbox[b*6+0]), loy = unmapf_u(bbox[b*6+1]), loz = unmapf_u(bbox[b*6+2]);
  float hix = unmapf_u(bbox[b*6+3]), hiy = unmapf_u(bbox[b*6+4]), hiz = unmapf_u(bbox[b*6+5]);
  int ix = min(GRES-1, max(0, (int)((p.x - lox) * ((float)GRES/(hix-lox)))));
  int iy = min(GRES-1, max(0, (int)((p.y - loy) * ((float)GRES/(hiy-loy)))));
  int iz = min(GRES-1, max(0, (int)((p.z - loz) * ((float)GRES/(hiz-loz)))));
  int cid = (iz*GRES + iy)*GRES + ix;
  cellId[m] = cid;
  atomicAdd(&counts[b*NCELL + cid], 1);
}

// ---------------- scan: per-batch exclusive prefix over NCELL counts ----------------
__global__ __launch_bounds__(1024) void scan_kernel(
    const int* __restrict__ counts, int* __restrict__ starts, int* __restrict__ cursor)
{
  __shared__ int part[1024];
  int b = blockIdx.x, t = threadIdx.x;
  const int* c = counts + b*NCELL;
  int* s = starts + b*(NCELL+1);
  int* cur = cursor + b*NCELL;
  int base = t*32, sum = 0;
  for (int i = 0; i < 32; ++i) sum += c[base+i];
  part[t] = sum; __syncthreads();
  for (int off = 1; off < 1024; off <<= 1){
    int v = (t >= off) ? part[t-off] : 0;
    __syncthreads();
    part[t] += v;
    __syncthreads();
  }
  int run = (t > 0) ? part[t-1] : 0;
  for (int i = 0; i < 32; ++i){ int cc = c[base+i]; s[base+i] = run; cur[base+i] = run; run += cc; }
  if (t == 1023) s[NCELL] = run;
}

// ---------------- scatter: cell-sorted pos4 + original idx ----------------
__global__ __launch_bounds__(256) void scatter_kernel(
    const float4* __restrict__ pos4, const int* __restrict__ cellId,
    int* __restrict__ cursor, float4* __restrict__ spos4, int* __restrict__ sidx)
{
  int m = blockIdx.x*256 + threadIdx.x;
  int b = m >> 13;
  int dst = atomicAdd(&cursor[b*NCELL + cellId[m]], 1);
  spos4[(b<<13) + dst] = pos4[m];
  sidx [(b<<13) + dst] = m & (NPTS-1);
}

// ---------------- kNN: one wave per query, expanding grid rings, exact top-16 ----------------
__global__ __launch_bounds__(256) void knn_grid_kernel(
    const float4* __restrict__ pos4, const float4* __restrict__ spos4,
    const int* __restrict__ sidx, const int* __restrict__ starts,
    const unsigned* __restrict__ bbox, int* __restrict__ idxout)
{
  const int tid = threadIdx.x, lane = tid & 63;
  const int g = blockIdx.x*4 + (tid >> 6);
  const int b = g >> 13, n = g & (NPTS-1);
  const float4 q = pos4[((size_t)b<<13) + n];
  const float4* sp = spos4 + ((size_t)b<<13);
  const int*    si = sidx  + ((size_t)b<<13);
  const int*    st = starts + b*(NCELL+1);

  float lox = unmapf_u(bbox[b*6+0]), loy = unmapf_u(bbox[b*6+1]), loz = unmapf_u(bbox[b*6+2]);
  float hix = unmapf_u(bbox[b*6+3]), hiy = unmapf_u(bbox[b*6+4]), hiz = unmapf_u(bbox[b*6+5]);
  float cwx = (hix-lox)*(1.0f/GRES), cwy = (hiy-loy)*(1.0f/GRES), cwz = (hiz-loz)*(1.0f/GRES);
  int cx = min(GRES-1, max(0, (int)((q.x - lox) * ((float)GRES/(hix-lox)))));
  int cy = min(GRES-1, max(0, (int)((q.y - loy) * ((float)GRES/(hiy-loy)))));
  int cz = min(GRES-1, max(0, (int)((q.z - loz) * ((float)GRES/(hiz-loz)))));

  unsigned khi = 0xFFFFFFFFu, klo = 0xFFFFFFFFu;   // distributed sorted list (lanes 0..15 per row)
  float Tf = __builtin_inff();

  auto insert = [&](unsigned ihi, unsigned ilo){
    unsigned phi = (unsigned)__builtin_amdgcn_update_dpp(0, (int)khi, 0x111, 0xF, 0xF, false);
    unsigned plo = (unsigned)__builtin_amdgcn_update_dpp(0, (int)klo, 0x111, 0xF, 0xF, false);
    bool gt  = (khi > ihi) || (khi == ihi && klo > ilo);
    bool pgt = ((lane & 15) != 0) && ((phi > ihi) || (phi == ihi && plo > ilo));
    khi = gt ? (pgt ? phi : ihi) : khi;
    klo = gt ? (pgt ? plo : ilo) : klo;
  };
  auto updT = [&](){
    unsigned t15 = (unsigned)__builtin_amdgcn_readlane((int)khi, 15);
    Tf = (t15 >= 0xFF800000u) ? __builtin_inff() : unmapf_u(t15);
  };

  for (int R = 1; R <= GRES-1; ++R){
    const int w = 2*R+1, w2 = w*w, nbox = w2*w;
    const bool first = (R == 1);
    for (int base = 0; base < nbox; base += 64){
      int e = base + lane;
      unsigned iz = (unsigned)e / (unsigned)w2;
      unsigned rem = (unsigned)e - iz*w2;
      unsigned iy = rem / (unsigned)w;
      unsigned ix = rem - iy*w;
      int dxx = (int)ix - R, dyy = (int)iy - R, dzz = (int)iz - R;
      int cheb = max(abs(dxx), max(abs(dyy), abs(dzz)));
      int gx = cx + dxx, gy = cy + dyy, gz = cz + dzz;
      bool take = (e < nbox) && (first || cheb == R)
               && gx >= 0 && gx < GRES && gy >= 0 && gy < GRES && gz >= 0 && gz < GRES;
      int cid = (gz*GRES + gy)*GRES + gx;
      int s0 = 0, s1 = 0;
      if (take){ s0 = st[cid]; s1 = st[cid+1]; }
      unsigned long long cm = __ballot(take && (s1 > s0));
      while (cm){
        int sl = (int)__builtin_ctzll(cm); cm &= cm - 1;
        int cs = __builtin_amdgcn_readlane(s0, sl);
        int ce = __builtin_amdgcn_readlane(s1, sl);
        for (int p0 = cs; p0 < ce; p0 += 64){
          int mm = p0 + lane;
          bool v = mm < ce;
          float4 c; int oi;
          if (v){ c = sp[mm]; oi = si[mm]; }
          else  { c = make_float4(0.f,0.f,0.f,__builtin_inff()); oi = 0x7fffffff; }
          float dot = __builtin_fmaf(c.z, q.z, __builtin_fmaf(c.y, q.y, __fmul_rn(c.x, q.x)));
          float d2  = __fsub_rn(__fadd_rn(q.w, c.w), __fadd_rn(dot, dot));
          bool ins = v && (d2 <= Tf);
          unsigned long long im = __ballot(ins);
          if (im){
            while (im){
              int s = (int)__builtin_ctzll(im); im &= im - 1;
              unsigned dvb = (unsigned)__builtin_amdgcn_readlane((int)__float_as_uint(d2), s);
              int ov = __builtin_amdgcn_readlane(oi, s);
              insert(mapf_u(dvb), (unsigned)ov);
            }
            updT();
          }
        }
      }
    }
    // termination bound: any unexamined point lies beyond >=1 face of the covered
    // box [cx-R .. cx+R] etc. Its d2 >= (min distance from q to a face plane)^2.
    // Faces that reached the grid boundary cannot hide points -> +inf.
    const float big = 1e30f;
    float dxlo = (cx-R <= 0)      ? big : (q.x - (lox + (float)(cx-R)*cwx));
    float dxhi = (cx+R >= GRES-1) ? big : ((lox + (float)(cx+R+1)*cwx) - q.x);
    float dylo = (cy-R <= 0)      ? big : (q.y - (loy + (float)(cy-R)*cwy));
    float dyhi = (cy+R >= GRES-1) ? big : ((loy + (float)(cy+R+1)*cwy) - q.y);
    float dzlo = (cz-R <= 0)      ? big : (q.z - (loz + (float)(cz-R)*cwz));
    float dzhi = (cz+R >= GRES-1) ? big : ((loz + (float)(cz+R+1)*cwz) - q.z);
    float dmin = fminf(fminf(fminf(dxlo,dxhi), fminf(dylo,dyhi)), fminf(dzlo,dzhi));
    if (dmin >= 1e29f) break;                       // box covers entire grid
    dmin = fmaxf(dmin, 0.0f);
    float dmin2 = dmin*dmin;
    if (Tf + 1e-4f + Tf*1e-5f < dmin2) break;       // Tf=+inf while unfilled -> keep going
  }
  if (lane < KNNK) idxout[(size_t)g*KNNK + lane] = (int)klo;
}

// ---------------- fused transform: 4 waves x 2 points, single-slot staging ----------------
__global__ __launch_bounds__(256, 2) void fused_kernel(
    const float* __restrict__ x, const float* __restrict__ pos,
    const float* __restrict__ bq, const float* __restrict__ bk,
    const float* __restrict__ bv, const float* __restrict__ Wp1,
    const float* __restrict__ bp1, const float* __restrict__ bp2,
    const float* __restrict__ bg1, const float* __restrict__ bg2,
    const int* __restrict__ idxws, const unsigned short* __restrict__ wt,
    float* __restrict__ out)
{
  extern __shared__ char smem[];
  unsigned short* WTl = (unsigned short*)smem;               // 1 slot: 34816 B
  float* q_lds = (float*)(smem + 34816);                     // [8][128] f32 = 4096
  unsigned short* t_base = (unsigned short*)(smem + 38912);  // 4 waves x [2][16][136] = 34816
  float* blds = (float*)(smem + 73728);                      // 1280 f32

  const int tid = threadIdx.x;
  const int lane = tid & 63, w = tid >> 6;
  const int r = lane & 15, grp = lane >> 4;
  const int pbase = blockIdx.x * 8;
  const int b = pbase >> 13;

  auto stageW = [&](int s){
    const float4* src = (const float4*)(wt + (size_t)s*WELEM);
    float4* dst = (float4*)smem;
    for (int cix = tid; cix < WELEM/8; cix += 256) dst[cix] = src[cix];
  };
  auto ldB = [&](int ct, int kk) -> s16x8 {
    return *(const s16x8*)&WTl[(ct*16 + r)*WPAD + kk*32 + grp*8];
  };

  for (int e = tid; e < 1280; e += 256){
    float v;
    if      (e < 128)  v = bq[e];
    else if (e < 256)  v = bk[e-128];
    else if (e < 384)  v = bv[e-256];
    else if (e < 512)  v = bp2[e-384];
    else if (e < 640)  v = bg1[e-512];
    else if (e < 768)  v = bg2[e-640];
    else if (e < 896)  v = bp1[e-768];
    else               v = Wp1[e-896];
    blds[e] = v;
  }
  stageW(0);   // Wq

  int nbr[2]; float relx[2], rely[2], relz[2];
#pragma unroll
  for (int j = 0; j < 2; ++j){
    int gp = pbase + w*2 + j;
    nbr[j] = idxws[(size_t)gp*KNNK + r];
    const float* pq = pos + (size_t)gp*3;
    const float* pn = pos + ((size_t)b*NPTS + nbr[j])*3;
    relx[j] = pq[0]-pn[0]; rely[j] = pq[1]-pn[1]; relz[j] = pq[2]-pn[2];
  }
  s16x8 qa[4];
  {
    const float* xr = x + (size_t)(pbase + (r & 7))*CDIM;
#pragma unroll
    for (int kk = 0; kk < 4; ++kk) qa[kk] = cvt8(xr + kk*32 + grp*8);
  }
  __syncthreads();

  {
    f32x4 qacc[2] = { {0.f,0.f,0.f,0.f}, {0.f,0.f,0.f,0.f} };
#pragma unroll
    for (int c2 = 0; c2 < 2; ++c2){
      int ct = w*2 + c2;
#pragma unroll
      for (int kk = 0; kk < 4; ++kk)
        qacc[c2] = __builtin_amdgcn_mfma_f32_16x16x32_bf16(qa[kk], ldB(ct,kk), qacc[c2], 0,0,0);
    }
#pragma unroll
    for (int c2 = 0; c2 < 2; ++c2){
      int col = (w*2+c2)*16 + r;
#pragma unroll
      for (int jj = 0; jj < 4; ++jj){
        int row = grp*4 + jj;
        if (row < 8) q_lds[row*CDIM + col] = qacc[c2][jj] + blds[col];
      }
    }
  }
  s16x8 pf[2][4];
#pragma unroll
  for (int j = 0; j < 2; ++j)
#pragma unroll
    for (int kk = 0; kk < 4; ++kk){
      s16x8 f;
#pragma unroll
      for (int i = 0; i < 8; ++i){
        int kc = kk*32 + grp*8 + i;
        float s = relx[j]*blds[896+kc] + rely[j]*blds[1024+kc] + relz[j]*blds[1152+kc] + blds[768+kc];
        f[i] = (short)to_bf16(fmaxf(s, 0.f));
      }
      pf[j][kk] = f;
    }
  __syncthreads();
  stageW(3);         // Wp2
  __syncthreads();

  f32x4 at[2][8], av[2][8];
#pragma unroll
  for (int j=0;j<2;++j)
#pragma unroll
    for (int ct=0;ct<8;++ct) at[j][ct] = (f32x4){0.f,0.f,0.f,0.f};
#pragma unroll
  for (int ct=0;ct<8;++ct)
#pragma unroll
    for (int kk=0;kk<4;++kk){
      s16x8 bw = ldB(ct,kk);
#pragma unroll
      for (int j=0;j<2;++j)
        at[j][ct] = __builtin_amdgcn_mfma_f32_16x16x32_bf16(pf[j][kk], bw, at[j][ct], 0,0,0);
    }
#pragma unroll
  for (int j=0;j<2;++j)
#pragma unroll
    for (int ct=0;ct<8;++ct) av[j][ct] = at[j][ct];
  s16x8 nf[2][4];
#pragma unroll
  for (int j=0;j<2;++j)
#pragma unroll
    for (int kk=0;kk<4;++kk)
      nf[j][kk] = cvt8(x + ((size_t)b*NPTS + nbr[j])*CDIM + kk*32 + grp*8);

  __syncthreads();
  stageW(1);         // -Wk
  __syncthreads();
#pragma unroll
  for (int ct=0;ct<8;++ct)
#pragma unroll
    for (int kk=0;kk<4;++kk){
      s16x8 bw = ldB(ct,kk);
#pragma unroll
      for (int j=0;j<2;++j) at[j][ct] = __builtin_amdgcn_mfma_f32_16x16x32_bf16(nf[j][kk], bw, at[j][ct], 0,0,0);
    }
  __syncthreads();
  stageW(2);         // Wv
  __syncthreads();
#pragma unroll
  for (int ct=0;ct<8;++ct)
#pragma unroll
    for (int kk=0;kk<4;++kk){
      s16x8 bw = ldB(ct,kk);
#pragma unroll
      for (int j=0;j<2;++j) av[j][ct] = __builtin_amdgcn_mfma_f32_16x16x32_bf16(nf[j][kk], bw, av[j][ct], 0,0,0);
    }
#pragma unroll
  for (int j=0;j<2;++j){
    int prow = (w*2+j)*CDIM;
#pragma unroll
    for (int ct=0;ct<8;++ct){
      int col = ct*16+r;
      float add = q_lds[prow+col] + blds[384+col] - blds[128+col];
#pragma unroll
      for (int jj=0;jj<4;++jj) at[j][ct][jj] = (at[j][ct][jj] + add)*SCALE;
    }
  }
  __syncthreads();
  stageW(4);         // Wg1
  __syncthreads();

  unsigned short* tl = t_base + w*(2*16*WPAD);
#pragma unroll
  for (int j=0;j<2;++j)
#pragma unroll
    for (int ct=0;ct<8;++ct)
#pragma unroll
      for (int jj=0;jj<4;++jj)
        tl[(j*16 + grp*4+jj)*WPAD + ct*16 + r] = to_bf16(at[j][ct][jj]);
  s16x8 tf[2][4];
#pragma unroll
  for (int j=0;j<2;++j)
#pragma unroll
    for (int kk=0;kk<4;++kk)
      tf[j][kk] = *(const s16x8*)&tl[(j*16 + r)*WPAD + kk*32 + grp*8];
  f32x4 hacc[2][8];
#pragma unroll
  for (int j=0;j<2;++j)
#pragma unroll
    for (int ct=0;ct<8;++ct) hacc[j][ct] = (f32x4){0.f,0.f,0.f,0.f};
#pragma unroll
  for (int ct=0;ct<8;++ct)
#pragma unroll
    for (int kk=0;kk<4;++kk){
      s16x8 bw = ldB(ct,kk);
#pragma unroll
      for (int j=0;j<2;++j)
        hacc[j][ct] = __builtin_amdgcn_mfma_f32_16x16x32_bf16(tf[j][kk], bw, hacc[j][ct], 0,0,0);
    }
  __syncthreads();
  stageW(5);         // Wg2
  __syncthreads();
#pragma unroll
  for (int j=0;j<2;++j)
#pragma unroll
    for (int ct=0;ct<8;++ct){
      int col = ct*16+r; float bb = blds[512+col];
#pragma unroll
      for (int jj=0;jj<4;++jj)
        tl[(j*16+grp*4+jj)*WPAD + ct*16 + r] = to_bf16(fmaxf(hacc[j][ct][jj]+bb, 0.f));
    }
  s16x8 hf[2][4];
#pragma unroll
  for (int j=0;j<2;++j)
#pragma unroll
    for (int kk=0;kk<4;++kk)
      hf[j][kk] = *(const s16x8*)&tl[(j*16 + r)*WPAD + kk*32 + grp*8];
  f32x4 gacc[2][8];
#pragma unroll
  for (int j=0;j<2;++j)
#pragma unroll
    for (int ct=0;ct<8;++ct) gacc[j][ct] = (f32x4){0.f,0.f,0.f,0.f};
#pragma unroll
  for (int ct=0;ct<8;++ct)
#pragma unroll
    for (int kk=0;kk<4;++kk){
      s16x8 bw = ldB(ct,kk);
#pragma unroll
      for (int j=0;j<2;++j)
        gacc[j][ct] = __builtin_amdgcn_mfma_f32_16x16x32_bf16(hf[j][kk], bw, gacc[j][ct], 0,0,0);
    }
#pragma unroll
  for (int j=0;j<2;++j){
#pragma unroll
    for (int ct=0;ct<8;++ct){
      int col = ct*16+r;
      float gb = blds[640+col];
      float g0v = gacc[j][ct][0]+gb, g1v = gacc[j][ct][1]+gb;
      float g2v = gacc[j][ct][2]+gb, g3v = gacc[j][ct][3]+gb;
      float mx = fmaxf(fmaxf(g0v,g1v), fmaxf(g2v,g3v));
      mx = fmaxf(mx, __shfl_xor(mx,16));
      mx = fmaxf(mx, __shfl_xor(mx,32));
      float e0=__expf(g0v-mx), e1=__expf(g1v-mx), e2=__expf(g2v-mx), e3=__expf(g3v-mx);
      float vb = blds[256+col] + blds[384+col];
      float ss = e0+e1+e2+e3;
      float oo = e0*(av[j][ct][0]+vb) + e1*(av[j][ct][1]+vb)
               + e2*(av[j][ct][2]+vb) + e3*(av[j][ct][3]+vb);
      ss += __shfl_xor(ss,16); ss += __shfl_xor(ss,32);
      oo += __shfl_xor(oo,16); oo += __shfl_xor(oo,32);
      if (grp == 0) out[(size_t)(pbase + w*2 + j)*CDIM + col] = oo/ss;
    }
  }
}

extern "C" void kernel_launch(void* const* d_in, const int* in_sizes, int n_in,
                              void* d_out, int out_size, void* d_ws, size_t ws_size,
                              hipStream_t stream)
{
  const float* x    = (const float*)d_in[0];
  const float* pos  = (const float*)d_in[1];
  const float* Wq   = (const float*)d_in[2];
  const float* bq   = (const float*)d_in[3];
  const float* Wk   = (const float*)d_in[4];
  const float* bk   = (const float*)d_in[5];
  const float* Wv   = (const float*)d_in[6];
  const float* bv   = (const float*)d_in[7];
  const float* Wp1  = (const float*)d_in[8];
  const float* bp1  = (const float*)d_in[9];
  const float* Wp2  = (const float*)d_in[10];
  const float* bp2  = (const float*)d_in[11];
  const float* Wg1  = (const float*)d_in[12];
  const float* bg1  = (const float*)d_in[13];
  const float* Wg2  = (const float*)d_in[14];
  const float* bg2  = (const float*)d_in[15];
  float* out = (float*)d_out;

  char* ws = (char*)d_ws;
  int*            idxs   = (int*)ws;                          // 1,048,576
  unsigned short* wt     = (unsigned short*)(ws + 1048576);   //   208,896
  float4*         pos4   = (float4*)(ws + 1257472);           //   262,144
  float4*         spos4  = (float4*)(ws + 1519616);           //   262,144
  int*            sidxp  = (int*)(ws + 1781760);              //    65,536
  int*            cellId = (int*)(ws + 1847296);              //    65,536
  int*            counts = (int*)(ws + 1912832);              //   262,144
  int*            starts = (int*)(ws + 2174976);              //   262,400
  int*            cursor = (int*)(ws + 2437376);              //   262,144
  unsigned*       bbox   = (unsigned*)(ws + 2699520);         //        48

  hipFuncSetAttribute((const void*)fused_kernel,
                      hipFuncAttributeMaxDynamicSharedMemorySize, FLDS_BYTES);

  zero_init_kernel<<<256, 256, 0, stream>>>(counts, bbox);
  prep_kernel<<<472, 256, 0, stream>>>(Wq, Wk, Wv, Wp2, Wg1, Wg2, pos, wt, pos4, bbox);
  bin_count_kernel<<<64, 256, 0, stream>>>(pos4, bbox, counts, cellId);
  scan_kernel<<<2, 1024, 0, stream>>>(counts, starts, cursor);
  scatter_kernel<<<64, 256, 0, stream>>>(pos4, cellId, cursor, spos4, sidxp);
  knn_grid_kernel<<<4096, 256, 0, stream>>>(pos4, spos4, sidxp, starts, bbox, idxs);
  fused_kernel<<<2048, 256, FLDS_BYTES, stream>>>(x, pos, bq, bk, bv, Wp1, bp1, bp2,
                                                  bg1, bg2, idxs, wt, out);
}

// Round 6
// 250.390 us; speedup vs baseline: 81.2901x; 1.5624x over previous
//
#include <hip/hip_runtime.h>
#include <stdint.h>

#define NPTS 8192
#define CDIM 128
#define KNNK 16
#define WPAD 136
#define WELEM (CDIM*WPAD)          // 17408 elems per transposed weight image
#define SCALE 0.08838834764831845f
#define FLDS_BYTES 78848
#define GRES 32
#define NCELL (GRES*GRES*GRES)

typedef __attribute__((ext_vector_type(4))) float f32x4;
typedef __attribute__((ext_vector_type(8))) short s16x8;

__device__ __forceinline__ unsigned short to_bf16(float f){
  union { float f; unsigned int u; } v; v.f = f;
  return (unsigned short)((v.u + 0x7fffu + ((v.u >> 16) & 1u)) >> 16);
}

__device__ __forceinline__ s16x8 cvt8(const float* p){
  float4 lo = *(const float4*)p;
  float4 hi = *(const float4*)(p + 4);
  s16x8 f;
  f[0]=(short)to_bf16(lo.x); f[1]=(short)to_bf16(lo.y);
  f[2]=(short)to_bf16(lo.z); f[3]=(short)to_bf16(lo.w);
  f[4]=(short)to_bf16(hi.x); f[5]=(short)to_bf16(hi.y);
  f[6]=(short)to_bf16(hi.z); f[7]=(short)to_bf16(hi.w);
  return f;
}

__device__ __forceinline__ unsigned mapf_u(unsigned s){
  return s ^ (0x80000000u | (unsigned)(((int)s) >> 31));
}
__device__ __forceinline__ float unmapf_u(unsigned u){
  unsigned r = (u & 0x80000000u) ? (u ^ 0x80000000u) : ~u;
  return __uint_as_float(r);
}

// ---------------- zero_init: counts + bbox ----------------
__global__ __launch_bounds__(256) void zero_init_kernel(int* __restrict__ counts,
                                                        unsigned* __restrict__ bbox)
{
  int t = blockIdx.x*256 + threadIdx.x;
  if (t < 2*NCELL) counts[t] = 0;
  if (t < 12) bbox[t] = ((t % 6) < 3) ? 0xFFFFFFFFu : 0u;   // lo-slots=max, hi-slots=min
}

// ---------------- prep: weights->bf16 images, pos4 pack, bbox reduce ----------------
__global__ __launch_bounds__(256) void prep_kernel(
    const float* __restrict__ Wq, const float* __restrict__ Wk,
    const float* __restrict__ Wv, const float* __restrict__ Wp2,
    const float* __restrict__ Wg1, const float* __restrict__ Wg2,
    const float* __restrict__ pos,
    unsigned short* __restrict__ wt, float4* __restrict__ pos4,
    unsigned* __restrict__ bbox)
{
  int t = blockIdx.x*256 + threadIdx.x;
  if (t < 6*WELEM){
    int w = t / WELEM, rem = t % WELEM, c = rem / WPAD, i = rem % WPAD;
    const float* src = (w==0)?Wq:(w==1)?Wk:(w==2)?Wv:(w==3)?Wp2:(w==4)?Wg1:Wg2;
    float v = (i < CDIM) ? src[i*CDIM + c] : 0.0f;
    if (w == 1) v = -v;                     // store -Wk so k folds into the t accumulator
    wt[t] = to_bf16(v);
  } else {
    int m = t - 6*WELEM;                    // < 16384, wave-aligned to batch
    float xx = pos[m*3+0], yy = pos[m*3+1], zz = pos[m*3+2];
    float p2 = __fadd_rn(__fadd_rn(__fmul_rn(xx,xx), __fmul_rn(yy,yy)), __fmul_rn(zz,zz));
    pos4[m] = make_float4(xx, yy, zz, p2);
    // wave-level bbox reduce (mapped u32), one atomic set per wave
    unsigned mnx = mapf_u(__float_as_uint(xx)), mny = mapf_u(__float_as_uint(yy)), mnz = mapf_u(__float_as_uint(zz));
    unsigned mxx = mnx, mxy = mny, mxz = mnz;
#pragma unroll
    for (int off = 1; off < 64; off <<= 1){
      mnx = min(mnx, (unsigned)__shfl_xor((int)mnx, off));
      mny = min(mny, (unsigned)__shfl_xor((int)mny, off));
      mnz = min(mnz, (unsigned)__shfl_xor((int)mnz, off));
      mxx = max(mxx, (unsigned)__shfl_xor((int)mxx, off));
      mxy = max(mxy, (unsigned)__shfl_xor((int)mxy, off));
      mxz = max(mxz, (unsigned)__shfl_xor((int)mxz, off));
    }
    if ((threadIdx.x & 63) == 0){
      int b = m >> 13;
      atomicMin(&bbox[b*6+0], mnx); atomicMin(&bbox[b*6+1], mny); atomicMin(&bbox[b*6+2], mnz);
      atomicMax(&bbox[b*6+3], mxx); atomicMax(&bbox[b*6+4], mxy); atomicMax(&bbox[b*6+5], mxz);
    }
  }
}

// ---------------- bin_count ----------------
__global__ __launch_bounds__(256) void bin_count_kernel(
    const float4* __restrict__ pos4, const unsigned* __restrict__ bbox,
    int* __restrict__ counts, int* __restrict__ cellId)
{
  int m = blockIdx.x*256 + threadIdx.x;       // < 16384
  int b = m >> 13;
  float4 p = pos4[m];
  float lox = unmapf_u(bbox[b*6+0]), loy = unmapf_u(bbox[b*6+1]), loz = unmapf_u(bbox[b*6+2]);
  float hix = unmapf_u(bbox[b*6+3]), hiy = unmapf_u(bbox[b*6+4]), hiz = unmapf_u(bbox[b*6+5]);
  int ix = min(GRES-1, max(0, (int)((p.x - lox) * ((float)GRES/(hix-lox)))));
  int iy = min(GRES-1, max(0, (int)((p.y - loy) * ((float)GRES/(hiy-loy)))));
  int iz = min(GRES-1, max(0, (int)((p.z - loz) * ((float)GRES/(hiz-loz)))));
  int cid = (iz*GRES + iy)*GRES + ix;
  cellId[m] = cid;
  atomicAdd(&counts[b*NCELL + cid], 1);
}

// ---------------- scan: per-batch exclusive prefix over NCELL counts ----------------
__global__ __launch_bounds__(1024) void scan_kernel(
    const int* __restrict__ counts, int* __restrict__ starts, int* __restrict__ cursor)
{
  __shared__ int part[1024];
  int b = blockIdx.x, t = threadIdx.x;
  const int* c = counts + b*NCELL;
  int* s = starts + b*(NCELL+1);
  int* cur = cursor + b*NCELL;
  int base = t*32, sum = 0;
  for (int i = 0; i < 32; ++i) sum += c[base+i];
  part[t] = sum; __syncthreads();
  for (int off = 1; off < 1024; off <<= 1){
    int v = (t >= off) ? part[t-off] : 0;
    __syncthreads();
    part[t] += v;
    __syncthreads();
  }
  int run = (t > 0) ? part[t-1] : 0;
  for (int i = 0; i < 32; ++i){ int cc = c[base+i]; s[base+i] = run; cur[base+i] = run; run += cc; }
  if (t == 1023) s[NCELL] = run;
}

// ---------------- scatter: cell-sorted pos4, original idx packed in .w ----------------
__global__ __launch_bounds__(256) void scatter_kernel(
    const float4* __restrict__ pos4, const int* __restrict__ cellId,
    int* __restrict__ cursor, float4* __restrict__ spos4)
{
  int m = blockIdx.x*256 + threadIdx.x;
  int b = m >> 13;
  float4 p = pos4[m];
  int dst = atomicAdd(&cursor[b*NCELL + cellId[m]], 1);
  spos4[(b<<13) + dst] = make_float4(p.x, p.y, p.z, __uint_as_float((unsigned)(m & (NPTS-1))));
}

// ---------------- kNN: one wave/query, expanding rings, ROW-batched segments ----------------
// Cells are x-fastest in the sorted array, so a run of cells (gz,gy,[gx0..gx1]) is ONE
// contiguous candidate segment. Ring R>=2 = 8R full rows + 2(2R-1)^2 edge cells
// (8R(2R+1) + 2(2R-1)^2 = 24R^2+2 = exact ring cell count).
__global__ __launch_bounds__(256) void knn_grid_kernel(
    const float4* __restrict__ pos4, const float4* __restrict__ spos4,
    const int* __restrict__ starts, const unsigned* __restrict__ bbox,
    int* __restrict__ idxout)
{
  const int tid = threadIdx.x, lane = tid & 63;
  const int g = blockIdx.x*4 + (tid >> 6);
  const int b = g >> 13, n = g & (NPTS-1);
  const float4 q = pos4[((size_t)b<<13) + n];
  const float4* sp = spos4 + ((size_t)b<<13);
  const int*    st = starts + b*(NCELL+1);

  float lox = unmapf_u(bbox[b*6+0]), loy = unmapf_u(bbox[b*6+1]), loz = unmapf_u(bbox[b*6+2]);
  float hix = unmapf_u(bbox[b*6+3]), hiy = unmapf_u(bbox[b*6+4]), hiz = unmapf_u(bbox[b*6+5]);
  float cwx = (hix-lox)*(1.0f/GRES), cwy = (hiy-loy)*(1.0f/GRES), cwz = (hiz-loz)*(1.0f/GRES);
  int cx = min(GRES-1, max(0, (int)((q.x - lox) * ((float)GRES/(hix-lox)))));
  int cy = min(GRES-1, max(0, (int)((q.y - loy) * ((float)GRES/(hiy-loy)))));
  int cz = min(GRES-1, max(0, (int)((q.z - loz) * ((float)GRES/(hiz-loz)))));

  unsigned khi = 0xFFFFFFFFu, klo = 0xFFFFFFFFu;   // distributed sorted list (lanes 0..15 per row)
  float Tf = __builtin_inff();

  auto insert = [&](unsigned ihi, unsigned ilo){
    unsigned phi = (unsigned)__builtin_amdgcn_update_dpp(0, (int)khi, 0x111, 0xF, 0xF, false);
    unsigned plo = (unsigned)__builtin_amdgcn_update_dpp(0, (int)klo, 0x111, 0xF, 0xF, false);
    bool gt  = (khi > ihi) || (khi == ihi && klo > ilo);
    bool pgt = ((lane & 15) != 0) && ((phi > ihi) || (phi == ihi && plo > ilo));
    khi = gt ? (pgt ? phi : ihi) : khi;
    klo = gt ? (pgt ? plo : ilo) : klo;
  };
  auto updT = [&](){
    unsigned t15 = (unsigned)__builtin_amdgcn_readlane((int)khi, 15);
    Tf = (t15 >= 0xFF800000u) ? __builtin_inff() : unmapf_u(t15);
  };

  for (int R = 1; R <= GRES-1; ++R){
    const bool first = (R == 1);
    const int per = 8*R, w1 = 2*R-1;
    const int ntask = first ? 9 : (per + 2*w1*w1);
    for (int tb = 0; tb < ntask; tb += 64){
      int t = tb + lane;
      int dy = 0, dz = 0, gx0 = 0, gx1 = -1;
      bool valid = t < ntask;
      if (first){
        if (valid){ dy = t % 3 - 1; dz = t / 3 - 1; }
        gx0 = max(cx-1, 0); gx1 = min(cx+1, GRES-1);
      } else if (valid){
        if (t < per){                       // perimeter rows: full x-range
          int s2 = 2*(2*R+1);
          if (t < s2){ dz = (t < 2*R+1) ? -R : R; dy = t % (2*R+1) - R; }
          else { int u = t - s2; dy = (u & 1) ? R : -R; dz = (u >> 1) - (R-1); }
          gx0 = max(cx-R, 0); gx1 = min(cx+R, GRES-1);
        } else {                            // interior rows: two edge cells
          int i = t - per, ri = i >> 1;
          dy = ri % w1 - (R-1); dz = ri / w1 - (R-1);
          int gx = cx + ((i & 1) ? R : -R);
          gx0 = gx; gx1 = gx;
          valid = gx >= 0 && gx <= GRES-1;
        }
      }
      int gy = cy + dy, gz = cz + dz;
      valid = valid && gy >= 0 && gy < GRES && gz >= 0 && gz < GRES && gx0 <= gx1;
      int s0 = 0, s1 = 0;
      if (valid){ int cb = (gz*GRES + gy)*GRES; s0 = st[cb + gx0]; s1 = st[cb + gx1 + 1]; }
      unsigned long long cm = __ballot(valid && (s1 > s0));
      while (cm){
        int sl = (int)__builtin_ctzll(cm); cm &= cm - 1;
        int cs = __builtin_amdgcn_readlane(s0, sl);
        int ce = __builtin_amdgcn_readlane(s1, sl);
        for (int p0 = cs; p0 < ce; p0 += 64){
          int mm = p0 + lane;
          bool v = mm < ce;
          float4 c = v ? sp[mm] : make_float4(0.f,0.f,0.f,0.f);
          // c2 recomputed with prep's exact op order -> bit-identical d2
          float c2  = __fadd_rn(__fadd_rn(__fmul_rn(c.x,c.x), __fmul_rn(c.y,c.y)), __fmul_rn(c.z,c.z));
          float dot = __builtin_fmaf(c.z, q.z, __builtin_fmaf(c.y, q.y, __fmul_rn(c.x, q.x)));
          float d2  = __fsub_rn(__fadd_rn(q.w, c2), __fadd_rn(dot, dot));
          int oi = __float_as_int(c.w);
          bool ins = v && (d2 <= Tf);
          unsigned long long im = __ballot(ins);
          if (im){
            while (im){
              int s = (int)__builtin_ctzll(im); im &= im - 1;
              unsigned dvb = (unsigned)__builtin_amdgcn_readlane((int)__float_as_uint(d2), s);
              int ov = __builtin_amdgcn_readlane(oi, s);
              insert(mapf_u(dvb), (unsigned)ov);
            }
            updT();
          }
        }
      }
    }
    // termination: any unexamined point lies beyond >=1 face plane of the covered box
    const float big = 1e30f;
    float dxlo = (cx-R <= 0)      ? big : (q.x - (lox + (float)(cx-R)*cwx));
    float dxhi = (cx+R >= GRES-1) ? big : ((lox + (float)(cx+R+1)*cwx) - q.x);
    float dylo = (cy-R <= 0)      ? big : (q.y - (loy + (float)(cy-R)*cwy));
    float dyhi = (cy+R >= GRES-1) ? big : ((loy + (float)(cy+R+1)*cwy) - q.y);
    float dzlo = (cz-R <= 0)      ? big : (q.z - (loz + (float)(cz-R)*cwz));
    float dzhi = (cz+R >= GRES-1) ? big : ((loz + (float)(cz+R+1)*cwz) - q.z);
    float dmin = fminf(fminf(fminf(dxlo,dxhi), fminf(dylo,dyhi)), fminf(dzlo,dzhi));
    if (dmin >= 1e29f) break;                       // box covers entire grid
    dmin = fmaxf(dmin, 0.0f);
    float dmin2 = dmin*dmin;
    if (Tf + 1e-4f + Tf*1e-5f < dmin2) break;       // Tf=+inf while unfilled -> keep going
  }
  if (lane < KNNK) idxout[(size_t)g*KNNK + lane] = (int)klo;
}

// ---------------- fused transform: 4 waves x 2 points, single-slot staging ----------------
__global__ __launch_bounds__(256, 2) void fused_kernel(
    const float* __restrict__ x, const float* __restrict__ pos,
    const float* __restrict__ bq, const float* __restrict__ bk,
    const float* __restrict__ bv, const float* __restrict__ Wp1,
    const float* __restrict__ bp1, const float* __restrict__ bp2,
    const float* __restrict__ bg1, const float* __restrict__ bg2,
    const int* __restrict__ idxws, const unsigned short* __restrict__ wt,
    float* __restrict__ out)
{
  extern __shared__ char smem[];
  unsigned short* WTl = (unsigned short*)smem;               // 1 slot: 34816 B
  float* q_lds = (float*)(smem + 34816);                     // [8][128] f32 = 4096
  unsigned short* t_base = (unsigned short*)(smem + 38912);  // 4 waves x [2][16][136] = 34816
  float* blds = (float*)(smem + 73728);                      // 1280 f32

  const int tid = threadIdx.x;
  const int lane = tid & 63, w = tid >> 6;
  const int r = lane & 15, grp = lane >> 4;
  const int pbase = blockIdx.x * 8;
  const int b = pbase >> 13;

  auto stageW = [&](int s){
    const float4* src = (const float4*)(wt + (size_t)s*WELEM);
    float4* dst = (float4*)smem;
    for (int cix = tid; cix < WELEM/8; cix += 256) dst[cix] = src[cix];
  };
  auto ldB = [&](int ct, int kk) -> s16x8 {
    return *(const s16x8*)&WTl[(ct*16 + r)*WPAD + kk*32 + grp*8];
  };

  for (int e = tid; e < 1280; e += 256){
    float v;
    if      (e < 128)  v = bq[e];
    else if (e < 256)  v = bk[e-128];
    else if (e < 384)  v = bv[e-256];
    else if (e < 512)  v = bp2[e-384];
    else if (e < 640)  v = bg1[e-512];
    else if (e < 768)  v = bg2[e-640];
    else if (e < 896)  v = bp1[e-768];
    else               v = Wp1[e-896];
    blds[e] = v;
  }
  stageW(0);   // Wq

  int nbr[2]; float relx[2], rely[2], relz[2];
#pragma unroll
  for (int j = 0; j < 2; ++j){
    int gp = pbase + w*2 + j;
    nbr[j] = idxws[(size_t)gp*KNNK + r];
    const float* pq = pos + (size_t)gp*3;
    const float* pn = pos + ((size_t)b*NPTS + nbr[j])*3;
    relx[j] = pq[0]-pn[0]; rely[j] = pq[1]-pn[1]; relz[j] = pq[2]-pn[2];
  }
  s16x8 qa[4];
  {
    const float* xr = x + (size_t)(pbase + (r & 7))*CDIM;
#pragma unroll
    for (int kk = 0; kk < 4; ++kk) qa[kk] = cvt8(xr + kk*32 + grp*8);
  }
  __syncthreads();

  {
    f32x4 qacc[2] = { {0.f,0.f,0.f,0.f}, {0.f,0.f,0.f,0.f} };
#pragma unroll
    for (int c2 = 0; c2 < 2; ++c2){
      int ct = w*2 + c2;
#pragma unroll
      for (int kk = 0; kk < 4; ++kk)
        qacc[c2] = __builtin_amdgcn_mfma_f32_16x16x32_bf16(qa[kk], ldB(ct,kk), qacc[c2], 0,0,0);
    }
#pragma unroll
    for (int c2 = 0; c2 < 2; ++c2){
      int col = (w*2+c2)*16 + r;
#pragma unroll
      for (int jj = 0; jj < 4; ++jj){
        int row = grp*4 + jj;
        if (row < 8) q_lds[row*CDIM + col] = qacc[c2][jj] + blds[col];
      }
    }
  }
  s16x8 pf[2][4];
#pragma unroll
  for (int j = 0; j < 2; ++j)
#pragma unroll
    for (int kk = 0; kk < 4; ++kk){
      s16x8 f;
#pragma unroll
      for (int i = 0; i < 8; ++i){
        int kc = kk*32 + grp*8 + i;
        float s = relx[j]*blds[896+kc] + rely[j]*blds[1024+kc] + relz[j]*blds[1152+kc] + blds[768+kc];
        f[i] = (short)to_bf16(fmaxf(s, 0.f));
      }
      pf[j][kk] = f;
    }
  __syncthreads();
  stageW(3);         // Wp2
  __syncthreads();

  f32x4 at[2][8], av[2][8];
#pragma unroll
  for (int j=0;j<2;++j)
#pragma unroll
    for (int ct=0;ct<8;++ct) at[j][ct] = (f32x4){0.f,0.f,0.f,0.f};
#pragma unroll
  for (int ct=0;ct<8;++ct)
#pragma unroll
    for (int kk=0;kk<4;++kk){
      s16x8 bw = ldB(ct,kk);
#pragma unroll
      for (int j=0;j<2;++j)
        at[j][ct] = __builtin_amdgcn_mfma_f32_16x16x32_bf16(pf[j][kk], bw, at[j][ct], 0,0,0);
    }
#pragma unroll
  for (int j=0;j<2;++j)
#pragma unroll
    for (int ct=0;ct<8;++ct) av[j][ct] = at[j][ct];
  s16x8 nf[2][4];
#pragma unroll
  for (int j=0;j<2;++j)
#pragma unroll
    for (int kk=0;kk<4;++kk)
      nf[j][kk] = cvt8(x + ((size_t)b*NPTS + nbr[j])*CDIM + kk*32 + grp*8);

  __syncthreads();
  stageW(1);         // -Wk
  __syncthreads();
#pragma unroll
  for (int ct=0;ct<8;++ct)
#pragma unroll
    for (int kk=0;kk<4;++kk){
      s16x8 bw = ldB(ct,kk);
#pragma unroll
      for (int j=0;j<2;++j) at[j][ct] = __builtin_amdgcn_mfma_f32_16x16x32_bf16(nf[j][kk], bw, at[j][ct], 0,0,0);
    }
  __syncthreads();
  stageW(2);         // Wv
  __syncthreads();
#pragma unroll
  for (int ct=0;ct<8;++ct)
#pragma unroll
    for (int kk=0;kk<4;++kk){
      s16x8 bw = ldB(ct,kk);
#pragma unroll
      for (int j=0;j<2;++j) av[j][ct] = __builtin_amdgcn_mfma_f32_16x16x32_bf16(nf[j][kk], bw, av[j][ct], 0,0,0);
    }
#pragma unroll
  for (int j=0;j<2;++j){
    int prow = (w*2+j)*CDIM;
#pragma unroll
    for (int ct=0;ct<8;++ct){
      int col = ct*16+r;
      float add = q_lds[prow+col] + blds[384+col] - blds[128+col];
#pragma unroll
      for (int jj=0;jj<4;++jj) at[j][ct][jj] = (at[j][ct][jj] + add)*SCALE;
    }
  }
  __syncthreads();
  stageW(4);         // Wg1
  __syncthreads();

  unsigned short* tl = t_base + w*(2*16*WPAD);
#pragma unroll
  for (int j=0;j<2;++j)
#pragma unroll
    for (int ct=0;ct<8;++ct)
#pragma unroll
      for (int jj=0;jj<4;++jj)
        tl[(j*16 + grp*4+jj)*WPAD + ct*16 + r] = to_bf16(at[j][ct][jj]);
  s16x8 tf[2][4];
#pragma unroll
  for (int j=0;j<2;++j)
#pragma unroll
    for (int kk=0;kk<4;++kk)
      tf[j][kk] = *(const s16x8*)&tl[(j*16 + r)*WPAD + kk*32 + grp*8];
  f32x4 hacc[2][8];
#pragma unroll
  for (int j=0;j<2;++j)
#pragma unroll
    for (int ct=0;ct<8;++ct) hacc[j][ct] = (f32x4){0.f,0.f,0.f,0.f};
#pragma unroll
  for (int ct=0;ct<8;++ct)
#pragma unroll
    for (int kk=0;kk<4;++kk){
      s16x8 bw = ldB(ct,kk);
#pragma unroll
      for (int j=0;j<2;++j)
        hacc[j][ct] = __builtin_amdgcn_mfma_f32_16x16x32_bf16(tf[j][kk], bw, hacc[j][ct], 0,0,0);
    }
  __syncthreads();
  stageW(5);         // Wg2
  __syncthreads();
#pragma unroll
  for (int j=0;j<2;++j)
#pragma unroll
    for (int ct=0;ct<8;++ct){
      int col = ct*16+r; float bb = blds[512+col];
#pragma unroll
      for (int jj=0;jj<4;++jj)
        tl[(j*16+grp*4+jj)*WPAD + ct*16 + r] = to_bf16(fmaxf(hacc[j][ct][jj]+bb, 0.f));
    }
  s16x8 hf[2][4];
#pragma unroll
  for (int j=0;j<2;++j)
#pragma unroll
    for (int kk=0;kk<4;++kk)
      hf[j][kk] = *(const s16x8*)&tl[(j*16 + r)*WPAD + kk*32 + grp*8];
  f32x4 gacc[2][8];
#pragma unroll
  for (int j=0;j<2;++j)
#pragma unroll
    for (int ct=0;ct<8;++ct) gacc[j][ct] = (f32x4){0.f,0.f,0.f,0.f};
#pragma unroll
  for (int ct=0;ct<8;++ct)
#pragma unroll
    for (int kk=0;kk<4;++kk){
      s16x8 bw = ldB(ct,kk);
#pragma unroll
      for (int j=0;j<2;++j)
        gacc[j][ct] = __builtin_amdgcn_mfma_f32_16x16x32_bf16(hf[j][kk], bw, gacc[j][ct], 0,0,0);
    }
#pragma unroll
  for (int j=0;j<2;++j){
#pragma unroll
    for (int ct=0;ct<8;++ct){
      int col = ct*16+r;
      float gb = blds[640+col];
      float g0v = gacc[j][ct][0]+gb, g1v = gacc[j][ct][1]+gb;
      float g2v = gacc[j][ct][2]+gb, g3v = gacc[j][ct][3]+gb;
      float mx = fmaxf(fmaxf(g0v,g1v), fmaxf(g2v,g3v));
      mx = fmaxf(mx, __shfl_xor(mx,16));
      mx = fmaxf(mx, __shfl_xor(mx,32));
      float e0=__expf(g0v-mx), e1=__expf(g1v-mx), e2=__expf(g2v-mx), e3=__expf(g3v-mx);
      float vb = blds[256+col] + blds[384+col];
      float ss = e0+e1+e2+e3;
      float oo = e0*(av[j][ct][0]+vb) + e1*(av[j][ct][1]+vb)
               + e2*(av[j][ct][2]+vb) + e3*(av[j][ct][3]+vb);
      ss += __shfl_xor(ss,16); ss += __shfl_xor(ss,32);
      oo += __shfl_xor(oo,16); oo += __shfl_xor(oo,32);
      if (grp == 0) out[(size_t)(pbase + w*2 + j)*CDIM + col] = oo/ss;
    }
  }
}

extern "C" void kernel_launch(void* const* d_in, const int* in_sizes, int n_in,
                              void* d_out, int out_size, void* d_ws, size_t ws_size,
                              hipStream_t stream)
{
  const float* x    = (const float*)d_in[0];
  const float* pos  = (const float*)d_in[1];
  const float* Wq   = (const float*)d_in[2];
  const float* bq   = (const float*)d_in[3];
  const float* Wk   = (const float*)d_in[4];
  const float* bk   = (const float*)d_in[5];
  const float* Wv   = (const float*)d_in[6];
  const float* bv   = (const float*)d_in[7];
  const float* Wp1  = (const float*)d_in[8];
  const float* bp1  = (const float*)d_in[9];
  const float* Wp2  = (const float*)d_in[10];
  const float* bp2  = (const float*)d_in[11];
  const float* Wg1  = (const float*)d_in[12];
  const float* bg1  = (const float*)d_in[13];
  const float* Wg2  = (const float*)d_in[14];
  const float* bg2  = (const float*)d_in[15];
  float* out = (float*)d_out;

  char* ws = (char*)d_ws;
  int*            idxs   = (int*)ws;                          // 1,048,576
  unsigned short* wt     = (unsigned short*)(ws + 1048576);   //   208,896
  float4*         pos4   = (float4*)(ws + 1257472);           //   262,144
  float4*         spos4  = (float4*)(ws + 1519616);           //   262,144
  int*            cellId = (int*)(ws + 1847296);              //    65,536
  int*            counts = (int*)(ws + 1912832);              //   262,144
  int*            starts = (int*)(ws + 2174976);              //   262,400
  int*            cursor = (int*)(ws + 2437376);              //   262,144
  unsigned*       bbox   = (unsigned*)(ws + 2699520);         //        48

  hipFuncSetAttribute((const void*)fused_kernel,
                      hipFuncAttributeMaxDynamicSharedMemorySize, FLDS_BYTES);

  zero_init_kernel<<<256, 256, 0, stream>>>(counts, bbox);
  prep_kernel<<<472, 256, 0, stream>>>(Wq, Wk, Wv, Wp2, Wg1, Wg2, pos, wt, pos4, bbox);
  bin_count_kernel<<<64, 256, 0, stream>>>(pos4, bbox, counts, cellId);
  scan_kernel<<<2, 1024, 0, stream>>>(counts, starts, cursor);
  scatter_kernel<<<64, 256, 0, stream>>>(pos4, cellId, cursor, spos4);
  knn_grid_kernel<<<4096, 256, 0, stream>>>(pos4, spos4, starts, bbox, idxs);
  fused_kernel<<<2048, 256, FLDS_BYTES, stream>>>(x, pos, bq, bk, bv, Wp1, bp1, bp2,
                                                  bg1, bg2, idxs, wt, out);
}